// Round 3
// baseline (189.680 us; speedup 1.0000x reference)
//
#include <hip/hip_runtime.h>
#include <math.h>

// Problem constants (fixed by the reference: B=1, N=262144, D=64, C=10, T=4096)
constexpr int N_PIX   = 262144;
constexpr int C_CLS   = 10;
constexpr int D_FEAT  = 64;
constexpr int T_TRIP  = 4096;
constexpr float ALPHA = 1.0f, BETA = 1.0f, GAMMA = 1.0f;

constexpr int MSE_F4       = N_PIX * 3 / 4;        // 196608 float4 pairs
constexpr int MSE_BLOCKS   = MSE_F4 / 512;         // 384 (2 float4 per thread)
constexpr int CE_BLOCKS    = N_PIX / 256;          // 1024 (256 rows/block)
constexpr int TRIP_BLOCKS  = T_TRIP / 4;           // 1024 (4 waves/block, 1 triplet/wave)
constexpr int TOTAL_BLOCKS = TRIP_BLOCKS + MSE_BLOCKS + CE_BLOCKS;   // 2432

constexpr int NACC = 32;   // spread-atomic accumulator lines
// d_ws layout: float accum[NACC]; unsigned counter;  (memset to 0 each call)

__global__ __launch_bounds__(256) void loss_kernel(
    const float* __restrict__ gt_img,
    const float* __restrict__ gt_seg,
    const float* __restrict__ inr_out,
    const float* __restrict__ seg_out,
    const float* __restrict__ feat,
    const int*   __restrict__ aidx,
    const int*   __restrict__ pidx,
    const int*   __restrict__ nidx,
    float*       __restrict__ ws,      // accum[32] + counter
    float*       __restrict__ out)
{
    __shared__ float s_seg[256 * C_CLS];   // 10 KB
    __shared__ float s_gt [256 * C_CLS];   // 10 KB
    __shared__ float s_red[4];
    __shared__ int   s_last;

    const int b   = blockIdx.x;
    const int tid = threadIdx.x;
    float local = 0.0f;

    if (b < TRIP_BLOCKS) {
        // ---- Triplet first: latency-bound gathers overlap the streaming blocks ----
        const int t    = b * 4 + (tid >> 6);
        const int lane = tid & 63;
        const int ai = aidx[t], pi = pidx[t], ni = nidx[t];
        const float a = feat[ai * D_FEAT + lane];
        const float p = feat[pi * D_FEAT + lane];
        const float n = feat[ni * D_FEAT + lane];
        float dp = (a - p) * (a - p);
        float dn = (a - n) * (a - n);
        #pragma unroll
        for (int off = 32; off > 0; off >>= 1) {
            dp += __shfl_down(dp, off, 64);
            dn += __shfl_down(dn, off, 64);
        }
        if (lane == 0)
            local = fmaxf(sqrtf(dp) - sqrtf(dn), 0.0f) * GAMMA;
    } else if (b < TRIP_BLOCKS + MSE_BLOCKS) {
        // ---- MSE: two float4 per thread, fully coalesced ----
        const int i0 = (b - TRIP_BLOCKS) * 512 + tid;
        const float4 a0 = ((const float4*)inr_out)[i0];
        const float4 g0 = ((const float4*)gt_img)[i0];
        const float4 a1 = ((const float4*)inr_out)[i0 + 256];
        const float4 g1 = ((const float4*)gt_img)[i0 + 256];
        const float dx0 = a0.x - g0.x, dy0 = a0.y - g0.y, dz0 = a0.z - g0.z, dw0 = a0.w - g0.w;
        const float dx1 = a1.x - g1.x, dy1 = a1.y - g1.y, dz1 = a1.z - g1.z, dw1 = a1.w - g1.w;
        local = (dx0*dx0 + dy0*dy0 + dz0*dz0 + dw0*dw0 +
                 dx1*dx1 + dy1*dy1 + dz1*dz1 + dw1*dw1) * (ALPHA / (float)(N_PIX * 3));
    } else {
        // ---- CE: 256 rows/block, float4 LDS staging ----
        const int base4 = (b - TRIP_BLOCKS - MSE_BLOCKS) * (256 * C_CLS / 4);
        const float4* seg4 = (const float4*)seg_out;
        const float4* gt4  = (const float4*)gt_seg;
        #pragma unroll
        for (int i = tid; i < 256 * C_CLS / 4; i += 256) {
            ((float4*)s_seg)[i] = seg4[base4 + i];
            ((float4*)s_gt )[i] = gt4 [base4 + i];
        }
        __syncthreads();   // block-uniform branch: safe
        const float* x = &s_seg[tid * C_CLS];
        const float* g = &s_gt [tid * C_CLS];
        float m = x[0];
        #pragma unroll
        for (int c = 1; c < C_CLS; ++c) m = fmaxf(m, x[c]);
        float s = 0.f, dot = 0.f;
        #pragma unroll
        for (int c = 0; c < C_CLS; ++c) {
            s   += __expf(x[c] - m);
            dot += g[c] * x[c];
        }
        const float lse = m + __logf(s);
        local = (lse - dot) * (BETA / (float)N_PIX);
    }

    // ---- block reduce ----
    #pragma unroll
    for (int off = 32; off > 0; off >>= 1)
        local += __shfl_down(local, off, 64);
    if ((tid & 63) == 0) s_red[tid >> 6] = local;
    __syncthreads();

    // ---- spread atomics into 32 lines + ticket; last block finishes ----
    if (tid == 0) {
        const float part = s_red[0] + s_red[1] + s_red[2] + s_red[3];
        atomicAdd(&ws[b & (NACC - 1)], part);      // device-scope, 32-way spread
        __threadfence();
        const unsigned old = atomicAdd((unsigned*)(ws + NACC), 1u);
        s_last = (old == (unsigned)(TOTAL_BLOCKS - 1));
    }
    __syncthreads();

    if (s_last && tid < 64) {
        // coherent read of the 32 accumulators (atomic read-modify-write of 0)
        float v = (tid < NACC) ? atomicAdd(&ws[tid], 0.0f) : 0.0f;
        #pragma unroll
        for (int off = 32; off > 0; off >>= 1)
            v += __shfl_down(v, off, 64);
        if (tid == 0) out[0] = v;
    }
}

extern "C" void kernel_launch(void* const* d_in, const int* in_sizes, int n_in,
                              void* d_out, int out_size, void* d_ws, size_t ws_size,
                              hipStream_t stream) {
    const float* gt_img      = (const float*)d_in[0];
    const float* gt_seg      = (const float*)d_in[1];
    const float* inr_output  = (const float*)d_in[2];
    const float* seg_output  = (const float*)d_in[3];
    const float* inr_feats   = (const float*)d_in[4];
    const int*   anchor_idx  = (const int*)d_in[5];
    const int*   pos_idx     = (const int*)d_in[6];
    const int*   neg_idx     = (const int*)d_in[7];
    float* out = (float*)d_out;
    float* ws  = (float*)d_ws;

    // zero the 32 accumulators + ticket counter (d_ws is re-poisoned 0xAA)
    hipMemsetAsync(ws, 0, (NACC + 1) * sizeof(float), stream);

    loss_kernel<<<TOTAL_BLOCKS, 256, 0, stream>>>(
        gt_img, gt_seg, inr_output, seg_output, inr_feats,
        anchor_idx, pos_idx, neg_idx, ws, out);
}

// Round 4
// 123.672 us; speedup vs baseline: 1.5337x; 1.5337x over previous
//
#include <hip/hip_runtime.h>
#include <math.h>

// Problem constants (fixed by the reference: B=1, N=262144, D=64, C=10, T=4096)
constexpr int N_PIX   = 262144;
constexpr int C_CLS   = 10;
constexpr int D_FEAT  = 64;
constexpr int T_TRIP  = 4096;
constexpr float ALPHA = 1.0f, BETA = 1.0f, GAMMA = 1.0f;

// Grid: CE first (heaviest stream), then MSE, then latency-bound triplet blocks.
// 1664 total blocks <= 1792 co-resident (7 blocks/CU @ 21 KB LDS) -> one wave, no tail.
constexpr int CE_BLOCKS    = N_PIX / 256;              // 1024 (256 rows/block)
constexpr int MSE_BLOCKS   = (N_PIX * 3 / 4) / 512;    // 384  (2 float4/thread)
constexpr int TRIP_BLOCKS  = T_TRIP / 16;              // 256  (4 waves x 4 triplets)
constexpr int TOTAL_BLOCKS = CE_BLOCKS + MSE_BLOCKS + TRIP_BLOCKS;   // 1664

__global__ __launch_bounds__(256) void loss_kernel(
    const float* __restrict__ gt_img,
    const float* __restrict__ gt_seg,
    const float* __restrict__ inr_out,
    const float* __restrict__ seg_out,
    const float* __restrict__ feat,
    const int*   __restrict__ aidx,
    const int*   __restrict__ pidx,
    const int*   __restrict__ nidx,
    float*       __restrict__ partials)
{
    __shared__ float s_seg[256 * C_CLS];   // 10 KB
    __shared__ float s_gt [256 * C_CLS];   // 10 KB
    __shared__ float s_red[4];

    const int b   = blockIdx.x;
    const int tid = threadIdx.x;
    float local = 0.0f;

    if (b < CE_BLOCKS) {
        // ---- CE: 256 rows/block, float4 LDS staging ----
        const int base4 = b * (256 * C_CLS / 4);
        const float4* seg4 = (const float4*)seg_out;
        const float4* gt4  = (const float4*)gt_seg;
        #pragma unroll
        for (int i = tid; i < 256 * C_CLS / 4; i += 256) {
            ((float4*)s_seg)[i] = seg4[base4 + i];
            ((float4*)s_gt )[i] = gt4 [base4 + i];
        }
        __syncthreads();   // block-uniform branch: safe
        const float* x = &s_seg[tid * C_CLS];   // 163k total conflict-cycles ~0.3us: ignore
        const float* g = &s_gt [tid * C_CLS];
        float m = x[0];
        #pragma unroll
        for (int c = 1; c < C_CLS; ++c) m = fmaxf(m, x[c]);
        float s = 0.f, dot = 0.f;
        #pragma unroll
        for (int c = 0; c < C_CLS; ++c) {
            s   += __expf(x[c] - m);
            dot += g[c] * x[c];
        }
        const float lse = m + __logf(s);
        local = (lse - dot) * (BETA / (float)N_PIX);
    } else if (b < CE_BLOCKS + MSE_BLOCKS) {
        // ---- MSE: two float4 per thread, fully coalesced ----
        const int i0 = (b - CE_BLOCKS) * 512 + tid;
        const float4 a0 = ((const float4*)inr_out)[i0];
        const float4 g0 = ((const float4*)gt_img)[i0];
        const float4 a1 = ((const float4*)inr_out)[i0 + 256];
        const float4 g1 = ((const float4*)gt_img)[i0 + 256];
        const float dx0 = a0.x - g0.x, dy0 = a0.y - g0.y, dz0 = a0.z - g0.z, dw0 = a0.w - g0.w;
        const float dx1 = a1.x - g1.x, dy1 = a1.y - g1.y, dz1 = a1.z - g1.z, dw1 = a1.w - g1.w;
        local = (dx0*dx0 + dy0*dy0 + dz0*dz0 + dw0*dw0 +
                 dx1*dx1 + dy1*dy1 + dz1*dz1 + dw1*dw1) * (ALPHA / (float)(N_PIX * 3));
    } else {
        // ---- Triplet: 4 waves x 4 triplets per block, lane = feature dim ----
        const int wave = tid >> 6, lane = tid & 63;
        const int tbase = (b - CE_BLOCKS - MSE_BLOCKS) * 16 + wave * 4;
        float acc = 0.0f;
        #pragma unroll
        for (int j = 0; j < 4; ++j) {
            const int t = tbase + j;
            const int ai = aidx[t], pi = pidx[t], ni = nidx[t];
            const float a = feat[ai * D_FEAT + lane];
            const float p = feat[pi * D_FEAT + lane];
            const float n = feat[ni * D_FEAT + lane];
            float dp = (a - p) * (a - p);
            float dn = (a - n) * (a - n);
            #pragma unroll
            for (int off = 32; off > 0; off >>= 1) {
                dp += __shfl_down(dp, off, 64);
                dn += __shfl_down(dn, off, 64);
            }
            if (lane == 0)
                acc += fmaxf(sqrtf(dp) - sqrtf(dn), 0.0f);
        }
        local = acc * GAMMA;   // nonzero only on lane 0 of each wave
    }

    // ---- block reduce -> ONE contention-free partial store per block ----
    #pragma unroll
    for (int off = 32; off > 0; off >>= 1)
        local += __shfl_down(local, off, 64);
    if ((tid & 63) == 0) s_red[tid >> 6] = local;
    __syncthreads();
    if (tid == 0)
        partials[b] = s_red[0] + s_red[1] + s_red[2] + s_red[3];
}

__global__ __launch_bounds__(256) void reduce_kernel(
    const float* __restrict__ partials, float* __restrict__ out)
{
    __shared__ float s_red[4];
    const int tid = threadIdx.x;
    float local = 0.0f;
    #pragma unroll
    for (int i = tid; i < TOTAL_BLOCKS; i += 256)   // 6-7 independent loads
        local += partials[i];
    #pragma unroll
    for (int off = 32; off > 0; off >>= 1)
        local += __shfl_down(local, off, 64);
    if ((tid & 63) == 0) s_red[tid >> 6] = local;
    __syncthreads();
    if (tid == 0)
        out[0] = s_red[0] + s_red[1] + s_red[2] + s_red[3];
}

extern "C" void kernel_launch(void* const* d_in, const int* in_sizes, int n_in,
                              void* d_out, int out_size, void* d_ws, size_t ws_size,
                              hipStream_t stream) {
    const float* gt_img      = (const float*)d_in[0];
    const float* gt_seg      = (const float*)d_in[1];
    const float* inr_output  = (const float*)d_in[2];
    const float* seg_output  = (const float*)d_in[3];
    const float* inr_feats   = (const float*)d_in[4];
    const int*   anchor_idx  = (const int*)d_in[5];
    const int*   pos_idx     = (const int*)d_in[6];
    const int*   neg_idx     = (const int*)d_in[7];
    float* out      = (float*)d_out;
    float* partials = (float*)d_ws;   // TOTAL_BLOCKS floats, fully rewritten each call

    loss_kernel<<<TOTAL_BLOCKS, 256, 0, stream>>>(
        gt_img, gt_seg, inr_output, seg_output, inr_feats,
        anchor_idx, pos_idx, neg_idx, partials);
    reduce_kernel<<<1, 256, 0, stream>>>(partials, out);
}

// Round 5
// 122.846 us; speedup vs baseline: 1.5440x; 1.0067x over previous
//
#include <hip/hip_runtime.h>
#include <math.h>

// Problem constants (fixed by the reference: B=1, N=262144, D=64, C=10, T=4096)
constexpr int N_PIX   = 262144;
constexpr int C_CLS   = 10;
constexpr int D_FEAT  = 64;
constexpr int T_TRIP  = 4096;
constexpr float ALPHA = 1.0f, BETA = 1.0f, GAMMA = 1.0f;

// Grid: CE (2 rows/thread, no LDS), MSE (2 float4/thread), triplet (4 waves x 4).
// 1152 blocks, all co-resident (4.5 blocks/CU, no LDS cap) -> single dispatch wave.
constexpr int CE_BLOCKS    = N_PIX / 512;              // 512
constexpr int MSE_BLOCKS   = (N_PIX * 3 / 4) / 512;    // 384
constexpr int TRIP_BLOCKS  = T_TRIP / 16;              // 256
constexpr int TOTAL_BLOCKS = CE_BLOCKS + MSE_BLOCKS + TRIP_BLOCKS;   // 1152

__device__ __forceinline__ float ce_row(const float2* __restrict__ seg2,
                                        const float2* __restrict__ gt2,
                                        int r)
{
    // row r: 10 floats at float2 indices [5r, 5r+5) — always 8-byte aligned
    float x[10], g[10];
    #pragma unroll
    for (int k = 0; k < 5; ++k) {
        const float2 xs = seg2[5 * r + k];
        const float2 gs = gt2 [5 * r + k];
        x[2*k] = xs.x; x[2*k+1] = xs.y;
        g[2*k] = gs.x; g[2*k+1] = gs.y;
    }
    float m = x[0];
    #pragma unroll
    for (int c = 1; c < C_CLS; ++c) m = fmaxf(m, x[c]);
    float s = 0.f, dot = 0.f;
    #pragma unroll
    for (int c = 0; c < C_CLS; ++c) {
        s   += __expf(x[c] - m);
        dot += g[c] * x[c];
    }
    return (m + __logf(s)) - dot;   // lse - <onehot, x>
}

__global__ __launch_bounds__(256) void loss_kernel(
    const float* __restrict__ gt_img,
    const float* __restrict__ gt_seg,
    const float* __restrict__ inr_out,
    const float* __restrict__ seg_out,
    const float* __restrict__ feat,
    const int*   __restrict__ aidx,
    const int*   __restrict__ pidx,
    const int*   __restrict__ nidx,
    float*       __restrict__ partials)
{
    __shared__ float s_red[4];

    const int b   = blockIdx.x;
    const int tid = threadIdx.x;
    float local = 0.0f;

    if (b < CE_BLOCKS) {
        // ---- CE: 512 rows/block, 2 rows/thread, direct float2 loads, no LDS ----
        const float2* seg2 = (const float2*)seg_out;
        const float2* gt2  = (const float2*)gt_seg;
        const int r0 = b * 512 + tid;
        local = (ce_row(seg2, gt2, r0) + ce_row(seg2, gt2, r0 + 256))
                * (BETA / (float)N_PIX);
    } else if (b < CE_BLOCKS + MSE_BLOCKS) {
        // ---- MSE: two float4 per thread, fully coalesced ----
        const int i0 = (b - CE_BLOCKS) * 512 + tid;
        const float4 a0 = ((const float4*)inr_out)[i0];
        const float4 g0 = ((const float4*)gt_img)[i0];
        const float4 a1 = ((const float4*)inr_out)[i0 + 256];
        const float4 g1 = ((const float4*)gt_img)[i0 + 256];
        const float dx0 = a0.x - g0.x, dy0 = a0.y - g0.y, dz0 = a0.z - g0.z, dw0 = a0.w - g0.w;
        const float dx1 = a1.x - g1.x, dy1 = a1.y - g1.y, dz1 = a1.z - g1.z, dw1 = a1.w - g1.w;
        local = (dx0*dx0 + dy0*dy0 + dz0*dz0 + dw0*dw0 +
                 dx1*dx1 + dy1*dy1 + dz1*dz1 + dw1*dw1) * (ALPHA / (float)(N_PIX * 3));
    } else {
        // ---- Triplet: 4 waves x 4 triplets per block, lane = feature dim ----
        const int wave = tid >> 6, lane = tid & 63;
        const int tbase = (b - CE_BLOCKS - MSE_BLOCKS) * 16 + wave * 4;
        float acc = 0.0f;
        #pragma unroll
        for (int j = 0; j < 4; ++j) {
            const int t = tbase + j;
            const int ai = aidx[t], pi = pidx[t], ni = nidx[t];
            const float a = feat[ai * D_FEAT + lane];
            const float p = feat[pi * D_FEAT + lane];
            const float n = feat[ni * D_FEAT + lane];
            float dp = (a - p) * (a - p);
            float dn = (a - n) * (a - n);
            #pragma unroll
            for (int off = 32; off > 0; off >>= 1) {
                dp += __shfl_down(dp, off, 64);
                dn += __shfl_down(dn, off, 64);
            }
            if (lane == 0)
                acc += fmaxf(sqrtf(dp) - sqrtf(dn), 0.0f);
        }
        local = acc * GAMMA;   // nonzero only on lane 0 of each wave
    }

    // ---- block reduce -> ONE contention-free partial store per block ----
    #pragma unroll
    for (int off = 32; off > 0; off >>= 1)
        local += __shfl_down(local, off, 64);
    if ((tid & 63) == 0) s_red[tid >> 6] = local;
    __syncthreads();
    if (tid == 0)
        partials[b] = s_red[0] + s_red[1] + s_red[2] + s_red[3];
}

__global__ __launch_bounds__(256) void reduce_kernel(
    const float* __restrict__ partials, float* __restrict__ out)
{
    __shared__ float s_red[4];
    const int tid = threadIdx.x;
    float local = 0.0f;
    #pragma unroll
    for (int i = tid; i < TOTAL_BLOCKS; i += 256)   // 4-5 independent loads
        local += partials[i];
    #pragma unroll
    for (int off = 32; off > 0; off >>= 1)
        local += __shfl_down(local, off, 64);
    if ((tid & 63) == 0) s_red[tid >> 6] = local;
    __syncthreads();
    if (tid == 0)
        out[0] = s_red[0] + s_red[1] + s_red[2] + s_red[3];
}

extern "C" void kernel_launch(void* const* d_in, const int* in_sizes, int n_in,
                              void* d_out, int out_size, void* d_ws, size_t ws_size,
                              hipStream_t stream) {
    const float* gt_img      = (const float*)d_in[0];
    const float* gt_seg      = (const float*)d_in[1];
    const float* inr_output  = (const float*)d_in[2];
    const float* seg_output  = (const float*)d_in[3];
    const float* inr_feats   = (const float*)d_in[4];
    const int*   anchor_idx  = (const int*)d_in[5];
    const int*   pos_idx     = (const int*)d_in[6];
    const int*   neg_idx     = (const int*)d_in[7];
    float* out      = (float*)d_out;
    float* partials = (float*)d_ws;   // TOTAL_BLOCKS floats, fully rewritten each call

    loss_kernel<<<TOTAL_BLOCKS, 256, 0, stream>>>(
        gt_img, gt_seg, inr_output, seg_output, inr_feats,
        anchor_idx, pos_idx, neg_idx, partials);
    reduce_kernel<<<1, 256, 0, stream>>>(partials, out);
}